// Round 1
// baseline (258.135 us; speedup 1.0000x reference)
//
#include <hip/hip_runtime.h>
#include <stdint.h>

#define B_ 2
#define S_ 2048
#define D_ 1024
#define H_ 16
#define HD_ 64
#define M_ (B_*S_)   // 4096

typedef __bf16 bf16;
typedef __attribute__((ext_vector_type(8))) __bf16 bf16x8;
typedef __attribute__((ext_vector_type(4))) float f32x4;

// ---------------- fp32 -> bf16 convert ----------------
__global__ void k_cvt(const float* __restrict__ src, bf16* __restrict__ dst, int n) {
    int idx = (blockIdx.x * blockDim.x + threadIdx.x) * 8;
    if (idx < n) {
        float4 a = *(const float4*)(src + idx);
        float4 b = *(const float4*)(src + idx + 4);
        bf16 o[8] = {(bf16)a.x,(bf16)a.y,(bf16)a.z,(bf16)a.w,
                     (bf16)b.x,(bf16)b.y,(bf16)b.z,(bf16)b.w};
        *(int4*)(dst + idx) = *(const int4*)o;
    }
}

// ---------------- QKV projection GEMM ----------------
// X [M_,D_] bf16, W [D_,D_] bf16 (row n = output col, contraction contiguous: NT gemm)
// z=0: Q -> [BH][S][HD] scaled by 1/8 ; z=1: K -> [BH][S][HD] ; z=2: V -> [BH][HD][S] (transposed)
__global__ __launch_bounds__(256) void k_gemm_qkv(
    const bf16* __restrict__ X,
    const bf16* __restrict__ Wq, const bf16* __restrict__ Wk, const bf16* __restrict__ Wv,
    const float* __restrict__ bq, const float* __restrict__ bk, const float* __restrict__ bv,
    bf16* __restrict__ Qo, bf16* __restrict__ Ko, bf16* __restrict__ Vo)
{
    const int z = blockIdx.z;
    const bf16* W = (z==0) ? Wq : (z==1) ? Wk : Wv;
    const float* bias = (z==0) ? bq : (z==1) ? bk : bv;
    const int n0 = blockIdx.x * 128;
    const int m0 = blockIdx.y * 128;
    const int t = threadIdx.x;
    const int w = t >> 6, lane = t & 63, quad = lane >> 4, l15 = lane & 15;
    const int mw = (w >> 1) * 64, nw = (w & 1) * 64;

    __shared__ __align__(16) bf16 As[128*64];
    __shared__ __align__(16) bf16 Bs[128*64];

    f32x4 acc[4][4];
    #pragma unroll
    for (int i = 0; i < 4; i++)
        #pragma unroll
        for (int j = 0; j < 4; j++)
            acc[i][j] = (f32x4){0.f,0.f,0.f,0.f};

    const int scol = (t & 7) * 8;
    const int srow = t >> 3;

    for (int k0 = 0; k0 < D_; k0 += 64) {
        #pragma unroll
        for (int c = 0; c < 4; c++) {
            int r = c*32 + srow;
            *(int4*)&As[r*64 + scol] = *(const int4*)&X[(size_t)(m0 + r)*D_ + k0 + scol];
            *(int4*)&Bs[r*64 + scol] = *(const int4*)&W[(size_t)(n0 + r)*D_ + k0 + scol];
        }
        __syncthreads();
        #pragma unroll
        for (int ks = 0; ks < 2; ks++) {
            bf16x8 af[4], bfr[4];
            #pragma unroll
            for (int i = 0; i < 4; i++)
                af[i] = *(const bf16x8*)&As[(mw + i*16 + l15)*64 + ks*32 + quad*8];
            #pragma unroll
            for (int j = 0; j < 4; j++)
                bfr[j] = *(const bf16x8*)&Bs[(nw + j*16 + l15)*64 + ks*32 + quad*8];
            #pragma unroll
            for (int i = 0; i < 4; i++)
                #pragma unroll
                for (int j = 0; j < 4; j++)
                    acc[i][j] = __builtin_amdgcn_mfma_f32_16x16x32_bf16(af[i], bfr[j], acc[i][j], 0, 0, 0);
        }
        __syncthreads();
    }

    const float scale = (z == 0) ? 0.125f : 1.0f;
    #pragma unroll
    for (int j = 0; j < 4; j++) {
        int n = n0 + nw + j*16 + l15;
        float bn = bias[n];
        int h = n >> 6, hd = n & 63;
        #pragma unroll
        for (int i = 0; i < 4; i++) {
            int mbase = m0 + mw + i*16 + quad*4;
            int b = mbase >> 11;
            int sbase = mbase & 2047;
            if (z == 2) {
                union { bf16 h4[4]; uint2 u; } pk;
                #pragma unroll
                for (int r = 0; r < 4; r++) pk.h4[r] = (bf16)(acc[i][j][r] + bn);
                *(uint2*)&Vo[((size_t)((b*H_ + h)*HD_ + hd))*S_ + sbase] = pk.u;
            } else {
                bf16* Out = (z == 0) ? Qo : Ko;
                #pragma unroll
                for (int r = 0; r < 4; r++) {
                    int s = sbase + r;
                    Out[((size_t)((b*H_ + h)*S_ + s))*HD_ + hd] = (bf16)((acc[i][j][r] + bn) * scale);
                }
            }
        }
    }
}

// ---------------- output projection GEMM (fp32 out) ----------------
__global__ __launch_bounds__(256) void k_gemm_out(
    const bf16* __restrict__ X, const bf16* __restrict__ W,
    const float* __restrict__ bias, float* __restrict__ Out)
{
    const int n0 = blockIdx.x * 128;
    const int m0 = blockIdx.y * 128;
    const int t = threadIdx.x;
    const int w = t >> 6, lane = t & 63, quad = lane >> 4, l15 = lane & 15;
    const int mw = (w >> 1) * 64, nw = (w & 1) * 64;

    __shared__ __align__(16) bf16 As[128*64];
    __shared__ __align__(16) bf16 Bs[128*64];

    f32x4 acc[4][4];
    #pragma unroll
    for (int i = 0; i < 4; i++)
        #pragma unroll
        for (int j = 0; j < 4; j++)
            acc[i][j] = (f32x4){0.f,0.f,0.f,0.f};

    const int scol = (t & 7) * 8;
    const int srow = t >> 3;

    for (int k0 = 0; k0 < D_; k0 += 64) {
        #pragma unroll
        for (int c = 0; c < 4; c++) {
            int r = c*32 + srow;
            *(int4*)&As[r*64 + scol] = *(const int4*)&X[(size_t)(m0 + r)*D_ + k0 + scol];
            *(int4*)&Bs[r*64 + scol] = *(const int4*)&W[(size_t)(n0 + r)*D_ + k0 + scol];
        }
        __syncthreads();
        #pragma unroll
        for (int ks = 0; ks < 2; ks++) {
            bf16x8 af[4], bfr[4];
            #pragma unroll
            for (int i = 0; i < 4; i++)
                af[i] = *(const bf16x8*)&As[(mw + i*16 + l15)*64 + ks*32 + quad*8];
            #pragma unroll
            for (int j = 0; j < 4; j++)
                bfr[j] = *(const bf16x8*)&Bs[(nw + j*16 + l15)*64 + ks*32 + quad*8];
            #pragma unroll
            for (int i = 0; i < 4; i++)
                #pragma unroll
                for (int j = 0; j < 4; j++)
                    acc[i][j] = __builtin_amdgcn_mfma_f32_16x16x32_bf16(af[i], bfr[j], acc[i][j], 0, 0, 0);
        }
        __syncthreads();
    }

    #pragma unroll
    for (int j = 0; j < 4; j++) {
        int n = n0 + nw + j*16 + l15;
        float bn = bias[n];
        #pragma unroll
        for (int i = 0; i < 4; i++) {
            int mbase = m0 + mw + i*16 + quad*4;
            #pragma unroll
            for (int r = 0; r < 4; r++)
                Out[(size_t)(mbase + r)*D_ + n] = acc[i][j][r] + bn;
        }
    }
}

// ---------------- fused attention ----------------
// Q [BH][S][HD] (pre-scaled by 1/8), K [BH][S][HD], Vt [BH][HD][S], mask [B,S]
// Ctx out: [M_, D_] bf16  ([B,S,H*HD])
__global__ __launch_bounds__(256) void k_attn(
    const bf16* __restrict__ Q, const bf16* __restrict__ K, const bf16* __restrict__ Vt,
    const float* __restrict__ mask, bf16* __restrict__ Ctx)
{
    const int bh = blockIdx.y;
    const int b = bh >> 4, h = bh & 15;
    const int q0 = blockIdx.x * 128;
    const int t = threadIdx.x;
    const int w = t >> 6, lane = t & 63, quad = lane >> 4, l15 = lane & 15;

    __shared__ __align__(16) bf16 Qs[128*64];
    __shared__ __align__(16) bf16 Ks[64*64];
    __shared__ __align__(16) bf16 Vs[64*64];
    __shared__ __align__(16) bf16 Ps[128*72];   // [q][k], stride 72 (16B-aligned rows)
    __shared__ float mts[64];
    __shared__ float lsum[128];

    // stage Q tile (fully contiguous 8192 elements)
    const bf16* Qbase = Q + ((size_t)bh*S_ + q0)*HD_;
    #pragma unroll
    for (int c = 0; c < 4; c++) {
        int off = (c*256 + t)*8;
        *(int4*)&Qs[off] = *(const int4*)&Qbase[off];
    }

    f32x4 cacc[2][4];
    #pragma unroll
    for (int i = 0; i < 2; i++)
        #pragma unroll
        for (int j = 0; j < 4; j++)
            cacc[i][j] = (f32x4){0.f,0.f,0.f,0.f};
    float lac[2] = {0.f, 0.f};

    const bf16* Kbh = K + (size_t)bh*S_*HD_;
    const bf16* Vbh = Vt + (size_t)bh*HD_*S_;

    for (int it = 0; it < S_/64; it++) {
        const int k0 = it*64;
        // stage K tile (contiguous 4096 elements)
        #pragma unroll
        for (int c = 0; c < 2; c++) {
            int off = (c*256 + t)*8;
            *(int4*)&Ks[off] = *(const int4*)&Kbh[(size_t)k0*HD_ + off];
        }
        // stage Vt tile: rows hd (stride S_ in global), contiguous within row
        #pragma unroll
        for (int c = 0; c < 2; c++) {
            int off = (c*256 + t)*8;
            int row = off >> 6, col = off & 63;
            *(int4*)&Vs[off] = *(const int4*)&Vbh[(size_t)row*S_ + k0 + col];
        }
        if (t < 64) mts[t] = (1.0f - mask[b*S_ + k0 + t]) * -10000.0f;
        __syncthreads();

        // S^T = K . Q^T : rows = kpos (64), cols = q ; wave w owns q cols [w*32, w*32+32)
        f32x4 st[4][2];
        #pragma unroll
        for (int mt = 0; mt < 4; mt++)
            #pragma unroll
            for (int nt = 0; nt < 2; nt++)
                st[mt][nt] = (f32x4){0.f,0.f,0.f,0.f};
        #pragma unroll
        for (int ks = 0; ks < 2; ks++) {
            bf16x8 af[4], bfr[2];
            #pragma unroll
            for (int mt = 0; mt < 4; mt++)
                af[mt] = *(const bf16x8*)&Ks[(mt*16 + l15)*64 + ks*32 + quad*8];
            #pragma unroll
            for (int nt = 0; nt < 2; nt++)
                bfr[nt] = *(const bf16x8*)&Qs[(w*32 + nt*16 + l15)*64 + ks*32 + quad*8];
            #pragma unroll
            for (int mt = 0; mt < 4; mt++)
                #pragma unroll
                for (int nt = 0; nt < 2; nt++)
                    st[mt][nt] = __builtin_amdgcn_mfma_f32_16x16x32_bf16(af[mt], bfr[nt], st[mt][nt], 0, 0, 0);
        }

        // polynomial sigmoid + write P[q][k] + accumulate row sums
        #pragma unroll
        for (int mt = 0; mt < 4; mt++) {
            float4 m4 = *(const float4*)&mts[mt*16 + quad*4];
            float mv[4] = {m4.x, m4.y, m4.z, m4.w};
            #pragma unroll
            for (int nt = 0; nt < 2; nt++) {
                int q = w*32 + nt*16 + l15;
                union { bf16 h4[4]; uint2 u; } pk;
                #pragma unroll
                for (int r = 0; r < 4; r++) {
                    float s = st[mt][nt][r] + mv[r];
                    float c = __builtin_amdgcn_fmed3f(s, -3.0f, 3.0f);
                    float u = fmaf(c*c, -0.01f, 0.25f);
                    float sg = fmaf(c, u, 0.5f);
                    sg = __builtin_amdgcn_fmed3f(sg, 0.01f, 0.99f);
                    lac[nt] += sg;
                    pk.h4[r] = (bf16)sg;
                }
                *(uint2*)&Ps[q*72 + mt*16 + quad*4] = pk.u;
            }
        }
        __syncthreads();

        // PV: ctx[q][hd] += P[q][k] * V[k][hd] ; wave w owns q rows [w*32, w*32+32)
        #pragma unroll
        for (int ks = 0; ks < 2; ks++) {
            bf16x8 pf[2], vf[4];
            #pragma unroll
            for (int mt2 = 0; mt2 < 2; mt2++)
                pf[mt2] = *(const bf16x8*)&Ps[(w*32 + mt2*16 + l15)*72 + ks*32 + quad*8];
            #pragma unroll
            for (int nt2 = 0; nt2 < 4; nt2++)
                vf[nt2] = *(const bf16x8*)&Vs[(nt2*16 + l15)*64 + ks*32 + quad*8];
            #pragma unroll
            for (int mt2 = 0; mt2 < 2; mt2++)
                #pragma unroll
                for (int nt2 = 0; nt2 < 4; nt2++)
                    cacc[mt2][nt2] = __builtin_amdgcn_mfma_f32_16x16x32_bf16(pf[mt2], vf[nt2], cacc[mt2][nt2], 0, 0, 0);
        }
        __syncthreads();
    }

    // reduce l across quads (rows of S^T spread over quads)
    #pragma unroll
    for (int nt = 0; nt < 2; nt++) {
        float v = lac[nt];
        v += __shfl_xor(v, 16);
        v += __shfl_xor(v, 32);
        if (quad == 0) lsum[w*32 + nt*16 + l15] = v;
    }
    __syncthreads();

    // epilogue: normalize and store ctx
    #pragma unroll
    for (int mt2 = 0; mt2 < 2; mt2++) {
        #pragma unroll
        for (int r = 0; r < 4; r++) {
            int q = w*32 + mt2*16 + quad*4 + r;
            float rinv = 1.0f / (lsum[q] + 1e-8f);
            size_t row = (size_t)(b*S_ + q0 + q);
            #pragma unroll
            for (int nt2 = 0; nt2 < 4; nt2++) {
                int hd = nt2*16 + l15;
                Ctx[row*D_ + h*HD_ + hd] = (bf16)(cacc[mt2][nt2][r] * rinv);
            }
        }
    }
}

extern "C" void kernel_launch(void* const* d_in, const int* in_sizes, int n_in,
                              void* d_out, int out_size, void* d_ws, size_t ws_size,
                              hipStream_t stream) {
    const float* hs   = (const float*)d_in[0];
    const float* mask = (const float*)d_in[1];
    const float* Wq   = (const float*)d_in[2];
    const float* bq   = (const float*)d_in[3];
    const float* Wk   = (const float*)d_in[4];
    const float* bk   = (const float*)d_in[5];
    const float* Wv   = (const float*)d_in[6];
    const float* bv   = (const float*)d_in[7];
    const float* Wo   = (const float*)d_in[8];
    const float* bo   = (const float*)d_in[9];
    float* out = (float*)d_out;

    char* ws = (char*)d_ws;
    const size_t MB = 1024*1024;
    bf16* hb   = (bf16*)(ws);            // [M_,D_]        8 MB
    bf16* wqb  = (bf16*)(ws + 8*MB);     // [D_,D_]        2 MB
    bf16* wkb  = (bf16*)(ws + 10*MB);
    bf16* wvb  = (bf16*)(ws + 12*MB);
    bf16* wob  = (bf16*)(ws + 14*MB);
    bf16* qb   = (bf16*)(ws + 16*MB);    // [BH][S][HD]    8 MB
    bf16* kb   = (bf16*)(ws + 24*MB);    // [BH][S][HD]    8 MB
    bf16* vtb  = (bf16*)(ws + 32*MB);    // [BH][HD][S]    8 MB
    bf16* ctxb = (bf16*)(ws + 40*MB);    // [M_,D_]        8 MB

    k_cvt<<<M_*D_/2048, 256, 0, stream>>>(hs, hb, M_*D_);
    k_cvt<<<D_*D_/2048, 256, 0, stream>>>(Wq, wqb, D_*D_);
    k_cvt<<<D_*D_/2048, 256, 0, stream>>>(Wk, wkb, D_*D_);
    k_cvt<<<D_*D_/2048, 256, 0, stream>>>(Wv, wvb, D_*D_);
    k_cvt<<<D_*D_/2048, 256, 0, stream>>>(Wo, wob, D_*D_);

    k_gemm_qkv<<<dim3(D_/128, M_/128, 3), 256, 0, stream>>>(
        hb, wqb, wkb, wvb, bq, bk, bv, qb, kb, vtb);

    k_attn<<<dim3(S_/128, B_*H_), 256, 0, stream>>>(qb, kb, vtb, mask, ctxb);

    k_gemm_out<<<dim3(D_/128, M_/128), 256, 0, stream>>>(ctxb, wob, bo, out);
}

// Round 2
// 215.653 us; speedup vs baseline: 1.1970x; 1.1970x over previous
//
#include <hip/hip_runtime.h>
#include <stdint.h>

#define B_ 2
#define S_ 2048
#define D_ 1024
#define H_ 16
#define HD_ 64
#define M_ (B_*S_)   // 4096

typedef __bf16 bf16;
typedef __attribute__((ext_vector_type(8))) __bf16 bf16x8;
typedef __attribute__((ext_vector_type(4))) float f32x4;

// async global->LDS, 16B per lane. LDS dest = uniform base + lane*16.
__device__ __forceinline__ void gload16(const bf16* g, bf16* l) {
    __builtin_amdgcn_global_load_lds(
        (const __attribute__((address_space(1))) void*)g,
        (__attribute__((address_space(3))) void*)l, 16, 0, 0);
}

// ---------------- fp32 -> bf16 converts ----------------
__global__ void k_cvt(const float* __restrict__ src, bf16* __restrict__ dst, int n) {
    int idx = (blockIdx.x * blockDim.x + threadIdx.x) * 8;
    if (idx < n) {
        float4 a = *(const float4*)(src + idx);
        float4 b = *(const float4*)(src + idx + 4);
        bf16 o[8] = {(bf16)a.x,(bf16)a.y,(bf16)a.z,(bf16)a.w,
                     (bf16)b.x,(bf16)b.y,(bf16)b.z,(bf16)b.w};
        *(int4*)(dst + idx) = *(const int4*)o;
    }
}

__global__ void k_cvt4(const float* __restrict__ s0, const float* __restrict__ s1,
                       const float* __restrict__ s2, const float* __restrict__ s3,
                       bf16* __restrict__ d0, bf16* __restrict__ d1,
                       bf16* __restrict__ d2, bf16* __restrict__ d3) {
    const float* s = (blockIdx.y==0)?s0:(blockIdx.y==1)?s1:(blockIdx.y==2)?s2:s3;
    bf16* d = (blockIdx.y==0)?d0:(blockIdx.y==1)?d1:(blockIdx.y==2)?d2:d3;
    int idx = (blockIdx.x * blockDim.x + threadIdx.x) * 8;
    float4 a = *(const float4*)(s + idx);
    float4 b = *(const float4*)(s + idx + 4);
    bf16 o[8] = {(bf16)a.x,(bf16)a.y,(bf16)a.z,(bf16)a.w,
                 (bf16)b.x,(bf16)b.y,(bf16)b.z,(bf16)b.w};
    *(int4*)(d + idx) = *(const int4*)o;
}

// ---------------- QKV projection GEMM (128x128 tile, DMA staging, swizzled LDS) ----
// z=0: Q -> [BH][S][HD] scaled 1/8 ; z=1: K -> [BH][S][HD] ; z=2: V -> [BH][HD][S]
__global__ __launch_bounds__(256) void k_gemm_qkv(
    const bf16* __restrict__ X,
    const bf16* __restrict__ Wq, const bf16* __restrict__ Wk, const bf16* __restrict__ Wv,
    const float* __restrict__ bq, const float* __restrict__ bk, const float* __restrict__ bv,
    bf16* __restrict__ Qo, bf16* __restrict__ Ko, bf16* __restrict__ Vo)
{
    const int z = blockIdx.z;
    const bf16* W = (z==0) ? Wq : (z==1) ? Wk : Wv;
    const float* bias = (z==0) ? bq : (z==1) ? bk : bv;
    const int n0 = blockIdx.x * 128;
    const int m0 = blockIdx.y * 128;
    const int t = threadIdx.x;
    const int w = t >> 6, lane = t & 63, quad = lane >> 4, l15 = lane & 15;
    const int lr = lane >> 3;                 // row-within-8
    const int lc = (lane & 7) ^ lr;           // swizzled source chunk
    const int sx = l15 & 7;                   // read-side xor
    const int mw = (w >> 1) * 64, nw = (w & 1) * 64;

    __shared__ __align__(16) bf16 As[128*64];
    __shared__ __align__(16) bf16 Bs[128*64];

    f32x4 acc[4][4];
    #pragma unroll
    for (int i = 0; i < 4; i++)
        #pragma unroll
        for (int j = 0; j < 4; j++)
            acc[i][j] = (f32x4){0.f,0.f,0.f,0.f};

    const bf16* gA = X + (size_t)(m0 + w*8 + lr)*D_ + lc*8;
    const bf16* gB = W + (size_t)(n0 + w*8 + lr)*D_ + lc*8;

    for (int k0 = 0; k0 < D_; k0 += 64) {
        #pragma unroll
        for (int c = 0; c < 4; c++) {
            gload16(gA + (size_t)c*32*D_ + k0, &As[c*2048 + w*512]);
            gload16(gB + (size_t)c*32*D_ + k0, &Bs[c*2048 + w*512]);
        }
        __syncthreads();
        #pragma unroll
        for (int ks = 0; ks < 2; ks++) {
            bf16x8 af[4], bfr[4];
            #pragma unroll
            for (int i = 0; i < 4; i++)
                af[i] = *(const bf16x8*)&As[(mw + i*16 + l15)*64 + (((ks*4+quad)^sx)*8)];
            #pragma unroll
            for (int j = 0; j < 4; j++)
                bfr[j] = *(const bf16x8*)&Bs[(nw + j*16 + l15)*64 + (((ks*4+quad)^sx)*8)];
            #pragma unroll
            for (int i = 0; i < 4; i++)
                #pragma unroll
                for (int j = 0; j < 4; j++)
                    acc[i][j] = __builtin_amdgcn_mfma_f32_16x16x32_bf16(af[i], bfr[j], acc[i][j], 0, 0, 0);
        }
        __syncthreads();
    }

    const float scale = (z == 0) ? 0.125f : 1.0f;
    #pragma unroll
    for (int j = 0; j < 4; j++) {
        int n = n0 + nw + j*16 + l15;
        float bn = bias[n];
        int h = n >> 6, hd = n & 63;
        #pragma unroll
        for (int i = 0; i < 4; i++) {
            int mbase = m0 + mw + i*16 + quad*4;
            int b = mbase >> 11;
            int sbase = mbase & 2047;
            if (z == 2) {
                union { bf16 h4[4]; uint2 u; } pk;
                #pragma unroll
                for (int r = 0; r < 4; r++) pk.h4[r] = (bf16)(acc[i][j][r] + bn);
                *(uint2*)&Vo[((size_t)((b*H_ + h)*HD_ + hd))*S_ + sbase] = pk.u;
            } else {
                bf16* Out = (z == 0) ? Qo : Ko;
                #pragma unroll
                for (int r = 0; r < 4; r++) {
                    int s = sbase + r;
                    Out[((size_t)((b*H_ + h)*S_ + s))*HD_ + hd] = (bf16)((acc[i][j][r] + bn) * scale);
                }
            }
        }
    }
}

// ---------------- output projection GEMM (64x128 tile -> 512 blocks) ----------------
__global__ __launch_bounds__(256) void k_gemm_out(
    const bf16* __restrict__ X, const bf16* __restrict__ W,
    const float* __restrict__ bias, float* __restrict__ Out)
{
    const int n0 = blockIdx.x * 128;
    const int m0 = blockIdx.y * 64;
    const int t = threadIdx.x;
    const int w = t >> 6, lane = t & 63, quad = lane >> 4, l15 = lane & 15;
    const int lr = lane >> 3;
    const int lc = (lane & 7) ^ lr;
    const int sx = l15 & 7;
    const int nw = w * 32;

    __shared__ __align__(16) bf16 As[64*64];
    __shared__ __align__(16) bf16 Bs[128*64];

    f32x4 acc[4][2];
    #pragma unroll
    for (int i = 0; i < 4; i++)
        #pragma unroll
        for (int j = 0; j < 2; j++)
            acc[i][j] = (f32x4){0.f,0.f,0.f,0.f};

    const bf16* gA = X + (size_t)(m0 + w*8 + lr)*D_ + lc*8;
    const bf16* gB = W + (size_t)(n0 + w*8 + lr)*D_ + lc*8;

    for (int k0 = 0; k0 < D_; k0 += 64) {
        #pragma unroll
        for (int c = 0; c < 2; c++)
            gload16(gA + (size_t)c*32*D_ + k0, &As[c*2048 + w*512]);
        #pragma unroll
        for (int c = 0; c < 4; c++)
            gload16(gB + (size_t)c*32*D_ + k0, &Bs[c*2048 + w*512]);
        __syncthreads();
        #pragma unroll
        for (int ks = 0; ks < 2; ks++) {
            bf16x8 af[4], bfr[2];
            #pragma unroll
            for (int i = 0; i < 4; i++)
                af[i] = *(const bf16x8*)&As[(i*16 + l15)*64 + (((ks*4+quad)^sx)*8)];
            #pragma unroll
            for (int j = 0; j < 2; j++)
                bfr[j] = *(const bf16x8*)&Bs[(nw + j*16 + l15)*64 + (((ks*4+quad)^sx)*8)];
            #pragma unroll
            for (int i = 0; i < 4; i++)
                #pragma unroll
                for (int j = 0; j < 2; j++)
                    acc[i][j] = __builtin_amdgcn_mfma_f32_16x16x32_bf16(af[i], bfr[j], acc[i][j], 0, 0, 0);
        }
        __syncthreads();
    }

    #pragma unroll
    for (int j = 0; j < 2; j++) {
        int n = n0 + nw + j*16 + l15;
        float bn = bias[n];
        #pragma unroll
        for (int i = 0; i < 4; i++) {
            int mbase = m0 + i*16 + quad*4;
            #pragma unroll
            for (int r = 0; r < 4; r++)
                Out[(size_t)(mbase + r)*D_ + n] = acc[i][j][r] + bn;
        }
    }
}

// ---------------- fused attention (q-tile 64 -> 1024 blocks) ----------------
// Q [BH][S][HD] (pre-scaled 1/8), K [BH][S][HD], Vt [BH][HD][S], mask [B,S]
__global__ __launch_bounds__(256) void k_attn(
    const bf16* __restrict__ Q, const bf16* __restrict__ K, const bf16* __restrict__ Vt,
    const float* __restrict__ mask, bf16* __restrict__ Ctx)
{
    const int bh = blockIdx.y;
    const int b = bh >> 4, h = bh & 15;
    const int q0 = blockIdx.x * 64;
    const int t = threadIdx.x;
    const int w = t >> 6, lane = t & 63, quad = lane >> 4, l15 = lane & 15;
    const int lr = lane >> 3;
    const int lc = (lane & 7) ^ lr;
    const int sx = l15 & 7;

    __shared__ __align__(16) bf16 Qs[64*64];
    __shared__ __align__(16) bf16 Ks[64*64];
    __shared__ __align__(16) bf16 Vs[64*64];
    __shared__ __align__(16) bf16 Ps[64*64];
    __shared__ float mts[64];
    __shared__ float lsum[64];

    // stage Q tile once (DMA, swizzled)
    const bf16* Qg = Q + ((size_t)bh*S_ + q0 + w*8 + lr)*HD_ + lc*8;
    #pragma unroll
    for (int c = 0; c < 2; c++)
        gload16(Qg + (size_t)c*32*HD_, &Qs[c*2048 + w*512]);
    __syncthreads();

    // each wave's Q fragment is invariant across the K loop: hold in regs
    bf16x8 bq[2];
    #pragma unroll
    for (int ks = 0; ks < 2; ks++)
        bq[ks] = *(const bf16x8*)&Qs[(w*16 + l15)*64 + (((ks*4+quad)^sx)*8)];

    f32x4 cacc[4];
    #pragma unroll
    for (int j = 0; j < 4; j++) cacc[j] = (f32x4){0.f,0.f,0.f,0.f};
    float lac = 0.f;

    const bf16* Kst = K + ((size_t)bh*S_ + w*8 + lr)*HD_ + lc*8;
    const bf16* Vst = Vt + ((size_t)bh*HD_ + w*8 + lr)*S_ + lc*8;

    for (int it = 0; it < S_/64; it++) {
        const int k0 = it*64;
        #pragma unroll
        for (int c = 0; c < 2; c++)
            gload16(Kst + (size_t)(k0 + c*32)*HD_, &Ks[c*2048 + w*512]);
        #pragma unroll
        for (int c = 0; c < 2; c++)
            gload16(Vst + (size_t)c*32*S_ + k0, &Vs[c*2048 + w*512]);
        if (t < 64) mts[t] = (1.0f - mask[(size_t)b*S_ + k0 + t]) * -10000.0f;
        __syncthreads();

        // S^T = K . Q^T : rows = kpos (64), cols = q (this wave's 16)
        f32x4 st[4];
        #pragma unroll
        for (int mt = 0; mt < 4; mt++) st[mt] = (f32x4){0.f,0.f,0.f,0.f};
        #pragma unroll
        for (int ks = 0; ks < 2; ks++) {
            bf16x8 af[4];
            #pragma unroll
            for (int mt = 0; mt < 4; mt++)
                af[mt] = *(const bf16x8*)&Ks[(mt*16 + l15)*64 + (((ks*4+quad)^sx)*8)];
            #pragma unroll
            for (int mt = 0; mt < 4; mt++)
                st[mt] = __builtin_amdgcn_mfma_f32_16x16x32_bf16(af[mt], bq[ks], st[mt], 0, 0, 0);
        }

        // polynomial sigmoid + P[q][k] write (swizzled) + row-sum accumulate
        #pragma unroll
        for (int mt = 0; mt < 4; mt++) {
            float4 m4 = *(const float4*)&mts[mt*16 + quad*4];
            float mv[4] = {m4.x, m4.y, m4.z, m4.w};
            union { bf16 h4[4]; uint2 u; } pk;
            #pragma unroll
            for (int r = 0; r < 4; r++) {
                float s = st[mt][r] + mv[r];
                float c = __builtin_amdgcn_fmed3f(s, -3.0f, 3.0f);
                float u = fmaf(c*c, -0.01f, 0.25f);
                float sg = fmaf(c, u, 0.5f);
                sg = __builtin_amdgcn_fmed3f(sg, 0.01f, 0.99f);
                lac += sg;
                pk.h4[r] = (bf16)sg;
            }
            int c8 = (mt*2 + (quad>>1)) ^ sx;
            *(uint2*)&Ps[(w*16 + l15)*64 + c8*8 + (quad&1)*4] = pk.u;
        }
        __syncthreads();

        // PV: ctx[q][hd] += P[q][k] * V[k][hd]
        #pragma unroll
        for (int ks = 0; ks < 2; ks++) {
            bf16x8 pf, vf[4];
            pf = *(const bf16x8*)&Ps[(w*16 + l15)*64 + (((ks*4+quad)^sx)*8)];
            #pragma unroll
            for (int nt = 0; nt < 4; nt++)
                vf[nt] = *(const bf16x8*)&Vs[(nt*16 + l15)*64 + (((ks*4+quad)^sx)*8)];
            #pragma unroll
            for (int nt = 0; nt < 4; nt++)
                cacc[nt] = __builtin_amdgcn_mfma_f32_16x16x32_bf16(pf, vf[nt], cacc[nt], 0, 0, 0);
        }
        __syncthreads();
    }

    // reduce l across quads
    {
        float v = lac;
        v += __shfl_xor(v, 16);
        v += __shfl_xor(v, 32);
        if (quad == 0) lsum[w*16 + l15] = v;
    }
    __syncthreads();

    // normalize + store ctx
    #pragma unroll
    for (int r = 0; r < 4; r++) {
        int q = w*16 + quad*4 + r;
        float rinv = 1.0f / (lsum[q] + 1e-8f);
        size_t row = (size_t)(b*S_ + q0 + q);
        #pragma unroll
        for (int nt = 0; nt < 4; nt++)
            Ctx[row*D_ + h*HD_ + nt*16 + l15] = (bf16)(cacc[nt][r] * rinv);
    }
}

extern "C" void kernel_launch(void* const* d_in, const int* in_sizes, int n_in,
                              void* d_out, int out_size, void* d_ws, size_t ws_size,
                              hipStream_t stream) {
    const float* hs   = (const float*)d_in[0];
    const float* mask = (const float*)d_in[1];
    const float* Wq   = (const float*)d_in[2];
    const float* bq   = (const float*)d_in[3];
    const float* Wk   = (const float*)d_in[4];
    const float* bk   = (const float*)d_in[5];
    const float* Wv   = (const float*)d_in[6];
    const float* bv   = (const float*)d_in[7];
    const float* Wo   = (const float*)d_in[8];
    const float* bo   = (const float*)d_in[9];
    float* out = (float*)d_out;

    char* ws = (char*)d_ws;
    const size_t MB = 1024*1024;
    bf16* hb   = (bf16*)(ws);            // [M_,D_]        8 MB
    bf16* wqb  = (bf16*)(ws + 8*MB);     // [D_,D_]        2 MB
    bf16* wkb  = (bf16*)(ws + 10*MB);
    bf16* wvb  = (bf16*)(ws + 12*MB);
    bf16* wob  = (bf16*)(ws + 14*MB);
    bf16* qb   = (bf16*)(ws + 16*MB);    // [BH][S][HD]    8 MB
    bf16* kb   = (bf16*)(ws + 24*MB);    // [BH][S][HD]    8 MB
    bf16* vtb  = (bf16*)(ws + 32*MB);    // [BH][HD][S]    8 MB
    bf16* ctxb = (bf16*)(ws + 40*MB);    // [M_,D_]        8 MB

    k_cvt<<<M_*D_/2048, 256, 0, stream>>>(hs, hb, M_*D_);
    k_cvt4<<<dim3(D_*D_/2048, 4), 256, 0, stream>>>(Wq, Wk, Wv, Wo, wqb, wkb, wvb, wob);

    k_gemm_qkv<<<dim3(D_/128, M_/128, 3), 256, 0, stream>>>(
        hb, wqb, wkb, wvb, bq, bk, bv, qb, kb, vtb);

    k_attn<<<dim3(S_/64, B_*H_), 256, 0, stream>>>(qb, kb, vtb, mask, ctxb);

    k_gemm_out<<<dim3(D_/128, M_/64), 256, 0, stream>>>(ctxb, wob, bo, out);
}

// Round 3
// 209.411 us; speedup vs baseline: 1.2327x; 1.0298x over previous
//
#include <hip/hip_runtime.h>
#include <stdint.h>

#define B_ 2
#define S_ 2048
#define D_ 1024
#define H_ 16
#define HD_ 64
#define M_ (B_*S_)   // 4096

typedef __bf16 bf16;
typedef __attribute__((ext_vector_type(8))) __bf16 bf16x8;
typedef __attribute__((ext_vector_type(4))) float f32x4;

// async global->LDS, 16B per lane. LDS dest = uniform base + lane*16.
__device__ __forceinline__ void gload16(const bf16* g, bf16* l) {
    __builtin_amdgcn_global_load_lds(
        (const __attribute__((address_space(1))) void*)g,
        (__attribute__((address_space(3))) void*)l, 16, 0, 0);
}

// ---------------- fp32 -> bf16 converts (single launch) ----------------
__global__ void k_cvt_all(const float* __restrict__ hs,
                          const float* __restrict__ Wq, const float* __restrict__ Wk,
                          const float* __restrict__ Wv, const float* __restrict__ Wo,
                          bf16* __restrict__ hb,
                          bf16* __restrict__ wqb, bf16* __restrict__ wkb,
                          bf16* __restrict__ wvb, bf16* __restrict__ wob) {
    int blk = blockIdx.x;
    const float* s; bf16* d; int base;
    if (blk < 2048) { s = hs; d = hb; base = blk; }
    else {
        int r = blk - 2048; int which = r >> 9; base = r & 511;
        s = (which==0)?Wq:(which==1)?Wk:(which==2)?Wv:Wo;
        d = (which==0)?wqb:(which==1)?wkb:(which==2)?wvb:wob;
    }
    int idx = base*2048 + threadIdx.x*8;
    float4 a = *(const float4*)(s + idx);
    float4 b = *(const float4*)(s + idx + 4);
    bf16 o[8] = {(bf16)a.x,(bf16)a.y,(bf16)a.z,(bf16)a.w,
                 (bf16)b.x,(bf16)b.y,(bf16)b.z,(bf16)b.w};
    *(int4*)(d + idx) = *(const int4*)o;
}

// ---------------- QKV projection GEMM (coalesced LDS-transpose epilogue) ----
// z=0: Q -> [BH][S][HD] scaled 1/8 ; z=1: K -> [BH][S][HD] ; z=2: V -> [BH][HD][S]
__global__ __launch_bounds__(256) void k_gemm_qkv(
    const bf16* __restrict__ X,
    const bf16* __restrict__ Wq, const bf16* __restrict__ Wk, const bf16* __restrict__ Wv,
    const float* __restrict__ bq, const float* __restrict__ bk, const float* __restrict__ bv,
    bf16* __restrict__ Qo, bf16* __restrict__ Ko, bf16* __restrict__ Vo)
{
    const int z = blockIdx.z;
    const bf16* W = (z==0) ? Wq : (z==1) ? Wk : Wv;
    const float* bias = (z==0) ? bq : (z==1) ? bk : bv;
    const int n0 = blockIdx.x * 128;
    const int m0 = blockIdx.y * 128;
    const int t = threadIdx.x;
    const int w = t >> 6, lane = t & 63, quad = lane >> 4, l15 = lane & 15;
    const int lr = lane >> 3;
    const int lc = (lane & 7) ^ lr;
    const int sx = l15 & 7;
    const int mw = (w >> 1) * 64, nw = (w & 1) * 64;

    __shared__ __align__(16) char smraw[128*136*2];  // 34816 B, aliased
    bf16* As  = (bf16*)smraw;               // [128][64]
    bf16* Bs  = (bf16*)(smraw + 16384);     // [128][64]
    bf16* epi = (bf16*)smraw;               // [128][136]

    f32x4 acc[4][4];
    #pragma unroll
    for (int i = 0; i < 4; i++)
        #pragma unroll
        for (int j = 0; j < 4; j++)
            acc[i][j] = (f32x4){0.f,0.f,0.f,0.f};

    const bf16* gA = X + (size_t)(m0 + w*8 + lr)*D_ + lc*8;
    const bf16* gB = W + (size_t)(n0 + w*8 + lr)*D_ + lc*8;

    for (int k0 = 0; k0 < D_; k0 += 64) {
        #pragma unroll
        for (int c = 0; c < 4; c++) {
            gload16(gA + (size_t)c*32*D_ + k0, &As[c*2048 + w*512]);
            gload16(gB + (size_t)c*32*D_ + k0, &Bs[c*2048 + w*512]);
        }
        __syncthreads();
        #pragma unroll
        for (int ks = 0; ks < 2; ks++) {
            bf16x8 af[4], bfr[4];
            #pragma unroll
            for (int i = 0; i < 4; i++)
                af[i] = *(const bf16x8*)&As[(mw + i*16 + l15)*64 + (((ks*4+quad)^sx)*8)];
            #pragma unroll
            for (int j = 0; j < 4; j++)
                bfr[j] = *(const bf16x8*)&Bs[(nw + j*16 + l15)*64 + (((ks*4+quad)^sx)*8)];
            #pragma unroll
            for (int i = 0; i < 4; i++)
                #pragma unroll
                for (int j = 0; j < 4; j++)
                    acc[i][j] = __builtin_amdgcn_mfma_f32_16x16x32_bf16(af[i], bfr[j], acc[i][j], 0, 0, 0);
        }
        __syncthreads();
    }

    // ---- epilogue: acc -> LDS (transposed layouts) -> coalesced global ----
    const float scale = (z == 0) ? 0.125f : 1.0f;
    if (z == 2) {
        // buffer [n=128][m stride 136]
        #pragma unroll
        for (int j = 0; j < 4; j++) {
            int n = nw + j*16 + l15;
            float bn = bias[n0 + n];
            #pragma unroll
            for (int i = 0; i < 4; i++) {
                int mloc = mw + i*16 + quad*4;
                union { bf16 h4[4]; uint2 u; } pk;
                #pragma unroll
                for (int r = 0; r < 4; r++) pk.h4[r] = (bf16)(acc[i][j][r] + bn);
                *(uint2*)&epi[n*136 + mloc] = pk.u;
            }
        }
    } else {
        // buffer [m=128][n stride 136]
        #pragma unroll
        for (int j = 0; j < 4; j++) {
            int n = nw + j*16 + l15;
            float bn = bias[n0 + n];
            #pragma unroll
            for (int i = 0; i < 4; i++) {
                int mloc = mw + i*16 + quad*4;
                #pragma unroll
                for (int r = 0; r < 4; r++)
                    epi[(mloc + r)*136 + n] = (bf16)((acc[i][j][r] + bn) * scale);
            }
        }
    }
    __syncthreads();
    if (z == 2) {
        #pragma unroll
        for (int kk = 0; kk < 8; kk++) {
            int c = t + 256*kk;
            int row = c >> 4;             // local n (dim)
            int mcol = (c & 15) * 8;      // local m (token)
            int4 val = *(const int4*)&epi[row*136 + mcol];
            int n = n0 + row; int hh = n >> 6, hd = n & 63;
            int m = m0 + mcol; int bb = m >> 11, s = m & 2047;
            *(int4*)&Vo[((size_t)((bb*H_ + hh)*HD_ + hd))*S_ + s] = val;
        }
    } else {
        bf16* Out = (z == 0) ? Qo : Ko;
        #pragma unroll
        for (int kk = 0; kk < 8; kk++) {
            int c = t + 256*kk;
            int row = c >> 4;             // local m (token)
            int ncol = (c & 15) * 8;      // local n (dim)
            int4 val = *(const int4*)&epi[row*136 + ncol];
            int m = m0 + row; int bb = m >> 11, s = m & 2047;
            int n = n0 + ncol; int hh = n >> 6, hd = n & 63;
            *(int4*)&Out[((size_t)((bb*H_ + hh)*S_ + s))*HD_ + hd] = val;
        }
    }
}

// ---------------- output projection GEMM (64x128 tile) ----------------
__global__ __launch_bounds__(256) void k_gemm_out(
    const bf16* __restrict__ X, const bf16* __restrict__ W,
    const float* __restrict__ bias, float* __restrict__ Out)
{
    const int n0 = blockIdx.x * 128;
    const int m0 = blockIdx.y * 64;
    const int t = threadIdx.x;
    const int w = t >> 6, lane = t & 63, quad = lane >> 4, l15 = lane & 15;
    const int lr = lane >> 3;
    const int lc = (lane & 7) ^ lr;
    const int sx = l15 & 7;
    const int nw = w * 32;

    __shared__ __align__(16) bf16 As[64*64];
    __shared__ __align__(16) bf16 Bs[128*64];

    f32x4 acc[4][2];
    #pragma unroll
    for (int i = 0; i < 4; i++)
        #pragma unroll
        for (int j = 0; j < 2; j++)
            acc[i][j] = (f32x4){0.f,0.f,0.f,0.f};

    const bf16* gA = X + (size_t)(m0 + w*8 + lr)*D_ + lc*8;
    const bf16* gB = W + (size_t)(n0 + w*8 + lr)*D_ + lc*8;

    for (int k0 = 0; k0 < D_; k0 += 64) {
        #pragma unroll
        for (int c = 0; c < 2; c++)
            gload16(gA + (size_t)c*32*D_ + k0, &As[c*2048 + w*512]);
        #pragma unroll
        for (int c = 0; c < 4; c++)
            gload16(gB + (size_t)c*32*D_ + k0, &Bs[c*2048 + w*512]);
        __syncthreads();
        #pragma unroll
        for (int ks = 0; ks < 2; ks++) {
            bf16x8 af[4], bfr[2];
            #pragma unroll
            for (int i = 0; i < 4; i++)
                af[i] = *(const bf16x8*)&As[(i*16 + l15)*64 + (((ks*4+quad)^sx)*8)];
            #pragma unroll
            for (int j = 0; j < 2; j++)
                bfr[j] = *(const bf16x8*)&Bs[(nw + j*16 + l15)*64 + (((ks*4+quad)^sx)*8)];
            #pragma unroll
            for (int i = 0; i < 4; i++)
                #pragma unroll
                for (int j = 0; j < 2; j++)
                    acc[i][j] = __builtin_amdgcn_mfma_f32_16x16x32_bf16(af[i], bfr[j], acc[i][j], 0, 0, 0);
        }
        __syncthreads();
    }

    #pragma unroll
    for (int j = 0; j < 2; j++) {
        int n = n0 + nw + j*16 + l15;
        float bn = bias[n];
        #pragma unroll
        for (int i = 0; i < 4; i++) {
            int mbase = m0 + i*16 + quad*4;
            #pragma unroll
            for (int r = 0; r < 4; r++)
                Out[(size_t)(mbase + r)*D_ + n] = acc[i][j][r] + bn;
        }
    }
}

// ---------------- fused attention v3 ----------------
// Q-tile 128/block (512 blocks). QK^T k-split across waves (Q all in regs),
// PV q-split. K/V double-buffered DMA. 2 barriers/iter.
__global__ __launch_bounds__(256, 2) void k_attn(
    const bf16* __restrict__ Q, const bf16* __restrict__ K, const bf16* __restrict__ Vt,
    const float* __restrict__ mask, bf16* __restrict__ Ctx)
{
    const int bh = blockIdx.y;
    const int b = bh >> 4, h = bh & 15;
    const int q0 = blockIdx.x * 128;
    const int t = threadIdx.x;
    const int w = t >> 6, lane = t & 63, quad = lane >> 4, l15 = lane & 15;
    const int lr = lane >> 3;
    const int lc = (lane & 7) ^ lr;
    const int sx = l15 & 7;

    __shared__ __align__(16) bf16 Ks[2][64*64];
    __shared__ __align__(16) bf16 Vs[2][64*64];
    __shared__ __align__(16) bf16 Ps[128*64];   // P[q][k], xor-swizzled rows
    __shared__ float lsumP[4][128];

    // Q fragments in registers: all 128 q rows (B-operand), 16 frags
    bf16x8 qf[8][2];
    const bf16* Qbase = Q + ((size_t)bh*S_ + q0)*HD_;
    #pragma unroll
    for (int qs = 0; qs < 8; qs++)
        #pragma unroll
        for (int ks = 0; ks < 2; ks++)
            qf[qs][ks] = *(const bf16x8*)&Qbase[(size_t)(qs*16 + l15)*HD_ + ks*32 + quad*8];

    f32x4 cacc[2][4];
    #pragma unroll
    for (int i = 0; i < 2; i++)
        #pragma unroll
        for (int j = 0; j < 4; j++)
            cacc[i][j] = (f32x4){0.f,0.f,0.f,0.f};
    float lac[8];
    #pragma unroll
    for (int qs = 0; qs < 8; qs++) lac[qs] = 0.f;

    const bf16* Kst = K + ((size_t)bh*S_ + w*8 + lr)*HD_ + lc*8;
    const bf16* Vst = Vt + ((size_t)bh*HD_ + w*8 + lr)*S_ + lc*8;

    // prologue: stage tile 0
    #pragma unroll
    for (int c = 0; c < 2; c++)
        gload16(Kst + (size_t)c*32*HD_, &Ks[0][c*2048 + w*512]);
    #pragma unroll
    for (int c = 0; c < 2; c++)
        gload16(Vst + (size_t)c*32*S_, &Vs[0][c*2048 + w*512]);
    __syncthreads();

    for (int it = 0; it < S_/64; it++) {
        const int cur = it & 1;
        const int k0 = it*64;

        // QK: S^T rows k in [w*16, w*16+16), all 128 q
        f32x4 st[8];
        #pragma unroll
        for (int qs = 0; qs < 8; qs++) st[qs] = (f32x4){0.f,0.f,0.f,0.f};
        #pragma unroll
        for (int ks = 0; ks < 2; ks++) {
            bf16x8 af = *(const bf16x8*)&Ks[cur][(w*16 + l15)*64 + (((ks*4+quad)^sx)*8)];
            #pragma unroll
            for (int qs = 0; qs < 8; qs++)
                st[qs] = __builtin_amdgcn_mfma_f32_16x16x32_bf16(af, qf[qs][ks], st[qs], 0, 0, 0);
        }

        // mask + polynomial sigmoid + P write (k = k0 + w*16 + quad*4 + r)
        float4 m4 = *(const float4*)&mask[(size_t)b*S_ + k0 + w*16 + quad*4];
        float mv[4] = {(1.0f-m4.x)*-10000.0f, (1.0f-m4.y)*-10000.0f,
                       (1.0f-m4.z)*-10000.0f, (1.0f-m4.w)*-10000.0f};
        const int c8 = (w*2 + (quad>>1)) ^ sx;
        #pragma unroll
        for (int qs = 0; qs < 8; qs++) {
            union { bf16 h4[4]; uint2 u; } pk;
            #pragma unroll
            for (int r = 0; r < 4; r++) {
                float s = st[qs][r] + mv[r];
                float c = __builtin_amdgcn_fmed3f(s, -3.0f, 3.0f);
                float u = fmaf(c*c, -0.01f, 0.25f);
                float sg = fmaf(c, u, 0.5f);
                sg = __builtin_amdgcn_fmed3f(sg, 0.01f, 0.99f);
                lac[qs] += sg;
                pk.h4[r] = (bf16)sg;
            }
            *(uint2*)&Ps[(qs*16 + l15)*64 + c8*8 + (quad&1)*4] = pk.u;
        }
        __syncthreads();   // B1: P visible to all; K-frag reads done

        // prefetch next K/V tile into other buffer (read by nobody now)
        if (it < S_/64 - 1) {
            const int nxt = cur ^ 1, k1 = k0 + 64;
            #pragma unroll
            for (int c = 0; c < 2; c++)
                gload16(Kst + (size_t)(k1 + c*32)*HD_, &Ks[nxt][c*2048 + w*512]);
            #pragma unroll
            for (int c = 0; c < 2; c++)
                gload16(Vst + (size_t)c*32*S_ + k1, &Vs[nxt][c*2048 + w*512]);
        }

        // PV: wave owns q in [w*32, w*32+32)
        #pragma unroll
        for (int ks = 0; ks < 2; ks++) {
            bf16x8 pf[2], vf[4];
            #pragma unroll
            for (int m2 = 0; m2 < 2; m2++)
                pf[m2] = *(const bf16x8*)&Ps[(w*32 + m2*16 + l15)*64 + (((ks*4+quad)^sx)*8)];
            #pragma unroll
            for (int nt = 0; nt < 4; nt++)
                vf[nt] = *(const bf16x8*)&Vs[cur][(nt*16 + l15)*64 + (((ks*4+quad)^sx)*8)];
            #pragma unroll
            for (int m2 = 0; m2 < 2; m2++)
                #pragma unroll
                for (int nt = 0; nt < 4; nt++)
                    cacc[m2][nt] = __builtin_amdgcn_mfma_f32_16x16x32_bf16(pf[m2], vf[nt], cacc[m2][nt], 0, 0, 0);
        }
        __syncthreads();   // B2: DMA drained; PV reads done
    }

    // cross-wave row-sum reduce (each wave holds partial over its k subset)
    #pragma unroll
    for (int qs = 0; qs < 8; qs++) {
        float v = lac[qs];
        v += __shfl_xor(v, 16);
        v += __shfl_xor(v, 32);
        if (quad == 0) lsumP[w][qs*16 + l15] = v;
    }
    __syncthreads();

    // normalize + store ctx
    #pragma unroll
    for (int m2 = 0; m2 < 2; m2++) {
        #pragma unroll
        for (int r = 0; r < 4; r++) {
            int q = w*32 + m2*16 + quad*4 + r;
            float s = lsumP[0][q] + lsumP[1][q] + lsumP[2][q] + lsumP[3][q];
            float rinv = 1.0f / (s + 1e-8f);
            size_t row = (size_t)(b*S_ + q0 + q);
            #pragma unroll
            for (int nt = 0; nt < 4; nt++)
                Ctx[row*D_ + h*HD_ + nt*16 + l15] = (bf16)(cacc[m2][nt][r] * rinv);
        }
    }
}

extern "C" void kernel_launch(void* const* d_in, const int* in_sizes, int n_in,
                              void* d_out, int out_size, void* d_ws, size_t ws_size,
                              hipStream_t stream) {
    const float* hs   = (const float*)d_in[0];
    const float* mask = (const float*)d_in[1];
    const float* Wq   = (const float*)d_in[2];
    const float* bq   = (const float*)d_in[3];
    const float* Wk   = (const float*)d_in[4];
    const float* bk   = (const float*)d_in[5];
    const float* Wv   = (const float*)d_in[6];
    const float* bv   = (const float*)d_in[7];
    const float* Wo   = (const float*)d_in[8];
    const float* bo   = (const float*)d_in[9];
    float* out = (float*)d_out;

    char* ws = (char*)d_ws;
    const size_t MB = 1024*1024;
    bf16* hb   = (bf16*)(ws);            // [M_,D_]        8 MB
    bf16* wqb  = (bf16*)(ws + 8*MB);     // [D_,D_]        2 MB
    bf16* wkb  = (bf16*)(ws + 10*MB);
    bf16* wvb  = (bf16*)(ws + 12*MB);
    bf16* wob  = (bf16*)(ws + 14*MB);
    bf16* qb   = (bf16*)(ws + 16*MB);    // [BH][S][HD]    8 MB
    bf16* kb   = (bf16*)(ws + 24*MB);    // [BH][S][HD]    8 MB
    bf16* vtb  = (bf16*)(ws + 32*MB);    // [BH][HD][S]    8 MB
    bf16* ctxb = (bf16*)(ws + 40*MB);    // [M_,D_]        8 MB

    k_cvt_all<<<2048 + 4*512, 256, 0, stream>>>(hs, Wq, Wk, Wv, Wo, hb, wqb, wkb, wvb, wob);

    k_gemm_qkv<<<dim3(D_/128, M_/128, 3), 256, 0, stream>>>(
        hb, wqb, wkb, wvb, bq, bk, bv, qb, kb, vtb);

    k_attn<<<dim3(S_/128, B_*H_), 256, 0, stream>>>(qb, kb, vtb, mask, ctxb);

    k_gemm_out<<<dim3(D_/128, M_/64), 256, 0, stream>>>(ctxb, wob, bo, out);
}